// Round 2
// baseline (3166.549 us; speedup 1.0000x reference)
//
#include <hip/hip_runtime.h>

#define NU 100000
#define NS 50000
#define NG 50
#define NW 20000
#define NT 10
#define CDIM 64
#define FDIM 384

// CSR build: HG blocks per edge type, LDS-binned histogram + ranked fill.
#define HG 8
#define HBINS 16000               // 64000 B LDS bins (<64KB static limit)
#define TOTB (4 * NS + NU + NG + NW + NT)  // 320060 unified bins

struct CsrArgs {
  const int* src[8];
  const int* dst[8];
  int E[8];
  int nb[8];
  int base[8];   // unified-bin base per type
  int* partial;  // [HG][TOTB]
  int* cnt;      // [TOTB]
  int* off[8];   // per-type CSR offsets (nb+1)
  int* adj[8];   // per-type adjacency (src ids grouped by dst)
};

// ---------------------------------------------------------------------------
// Pass 1: per-block LDS histogram of dst, multi-pass over bin ranges.
// No global atomics anywhere in the CSR build.
// ---------------------------------------------------------------------------
__global__ __launch_bounds__(256) void hist_all(CsrArgs a) {
  __shared__ int bins[HBINS];
  const int ty = blockIdx.x / HG, b = blockIdx.x % HG, t = threadIdx.x;
  const int* __restrict__ dst = a.dst[ty];
  const int E = a.E[ty], nb = a.nb[ty], ub0 = a.base[ty];
  const int npass = (nb + HBINS - 1) / HBINS;
  for (int p = 0; p < npass; ++p) {
    const int lo = p * HBINS;
    const int n = min(HBINS, nb - lo);
    for (int i = t; i < n; i += 256) bins[i] = 0;
    __syncthreads();
    for (int i = b * 256 + t; i < E; i += HG * 256) {
      int d = dst[i] - lo;
      if ((unsigned)d < (unsigned)n) atomicAdd(&bins[d], 1);
    }
    __syncthreads();
    for (int i = t; i < n; i += 256)
      a.partial[(size_t)b * TOTB + ub0 + lo + i] = bins[i];
    __syncthreads();
  }
}

// Column scan over blocks: partial[b][bin] -> exclusive per-block offset,
// cnt[bin] = total degree. Fully coalesced.
__global__ __launch_bounds__(256) void scan_blocks_all(int* __restrict__ partial,
                                                       int* __restrict__ cnt) {
  int bin = blockIdx.x * 256 + threadIdx.x;
  if (bin >= TOTB) return;
  int run = 0;
  for (int b = 0; b < HG; ++b) {
    int v = partial[(size_t)b * TOTB + bin];
    partial[(size_t)b * TOTB + bin] = run;
    run += v;
  }
  cnt[bin] = run;
}

// Per-type exclusive prefix sum of cnt -> off (one block per type).
__global__ __launch_bounds__(1024) void scan_off_all(CsrArgs a) {
  __shared__ int part[1024];
  const int ty = blockIdx.x, t = threadIdx.x;
  const int* __restrict__ cnt = a.cnt + a.base[ty];
  int* __restrict__ off = a.off[ty];
  const int N = a.nb[ty];
  const int chunk = (N + 1023) / 1024;
  const int lo = t * chunk, hi = min(N, lo + chunk);
  int s = 0;
  for (int i = lo; i < hi; ++i) s += cnt[i];
  part[t] = s;
  __syncthreads();
  for (int d = 1; d < 1024; d <<= 1) {
    int v = (t >= d) ? part[t - d] : 0;
    __syncthreads();
    part[t] += v;
    __syncthreads();
  }
  int carry = (t > 0) ? part[t - 1] : 0;
  for (int i = lo; i < hi; ++i) { off[i] = carry; carry += cnt[i]; }
  if (t == 1023) off[N] = part[1023];
}

// Pass 2: rank each edge with an LDS atomic, plain-store src into its slot.
// Same edge partition / pass structure as hist_all (must match).
__global__ __launch_bounds__(256) void fill_all(CsrArgs a) {
  __shared__ int bins[HBINS];
  const int ty = blockIdx.x / HG, b = blockIdx.x % HG, t = threadIdx.x;
  const int* __restrict__ dst = a.dst[ty];
  const int* __restrict__ src = a.src[ty];
  const int E = a.E[ty], nb = a.nb[ty], ub0 = a.base[ty];
  const int* __restrict__ off = a.off[ty];
  int* __restrict__ adj = a.adj[ty];
  const int* __restrict__ part = a.partial + (size_t)b * TOTB + ub0;
  const int npass = (nb + HBINS - 1) / HBINS;
  for (int p = 0; p < npass; ++p) {
    const int lo = p * HBINS;
    const int n = min(HBINS, nb - lo);
    for (int i = t; i < n; i += 256) bins[i] = 0;
    __syncthreads();
    for (int i = b * 256 + t; i < E; i += HG * 256) {
      int d = dst[i] - lo;
      if ((unsigned)d < (unsigned)n) {
        int r = atomicAdd(&bins[d], 1);
        adj[off[lo + d] + part[lo + d] + r] = src[i];
      }
    }
    __syncthreads();
  }
}

// ---------------------------------------------------------------------------
// Gather aggregation (mean fused). Wave per dst node; lane = channel.
// src indices broadcast via shfl; 256B coalesced row reads (L2/L3 resident).
// ---------------------------------------------------------------------------
__device__ __forceinline__ float gather_sum(const int* __restrict__ adj, int beg,
                                            int deg, const float* __restrict__ x,
                                            int lane) {
  float a0 = 0.f, a1 = 0.f, a2 = 0.f, a3 = 0.f;
  for (int j0 = 0; j0 < deg; j0 += 64) {
    int myj = j0 + lane;
    int s = (myj < deg) ? adj[beg + myj] : 0;
    int m = min(64, deg - j0);
    int j = 0;
    for (; j + 4 <= m; j += 4) {
      int s0 = __shfl(s, j, 64), s1 = __shfl(s, j + 1, 64);
      int s2 = __shfl(s, j + 2, 64), s3 = __shfl(s, j + 3, 64);
      a0 += x[(size_t)s0 * CDIM + lane];
      a1 += x[(size_t)s1 * CDIM + lane];
      a2 += x[(size_t)s2 * CDIM + lane];
      a3 += x[(size_t)s3 * CDIM + lane];
    }
    for (; j < m; ++j) a0 += x[(size_t)__shfl(s, j, 64) * CDIM + lane];
  }
  return (a0 + a1) + (a2 + a3);
}

__global__ __launch_bounds__(256) void agg_gather_k(const int* __restrict__ adj,
                                                    const int* __restrict__ off,
                                                    const float* __restrict__ x,
                                                    float* __restrict__ out, int N) {
  int wid = (blockIdx.x * 256 + threadIdx.x) >> 6;
  int lane = threadIdx.x & 63;
  if (wid >= N) return;
  int beg = off[wid], deg = off[wid + 1] - beg;
  float s = gather_sum(adj, beg, deg, x, lane);
  out[(size_t)wid * CDIM + lane] = (deg > 0) ? s / (float)deg : 0.f;
}

// Fused 4-type series aggregation (types 0,2,4,6 all have N=NS dsts).
struct Agg4Args {
  const int* adj[4];
  const int* off[4];
  const float* x[4];
  float* out[4];
};
__global__ __launch_bounds__(256) void agg_series4_k(Agg4Args a) {
  int ty = blockIdx.y;
  int wid = (blockIdx.x * 256 + threadIdx.x) >> 6;
  int lane = threadIdx.x & 63;
  if (wid >= NS) return;
  const int* off = a.off[ty];
  int beg = off[wid], deg = off[wid + 1] - beg;
  float s = gather_sum(a.adj[ty], beg, deg, a.x[ty], lane);
  a.out[ty][(size_t)wid * CDIM + lane] = (deg > 0) ? s / (float)deg : 0.f;
}

// High-degree dst types (genres ~3000/node, type ~5000/node): block per dst,
// 16 waves strided over the edge list, LDS reduce.
__global__ __launch_bounds__(1024) void agg_dense_k(const int* __restrict__ adj,
                                                    const int* __restrict__ off,
                                                    const float* __restrict__ x,
                                                    float* __restrict__ out, int N) {
  __shared__ float red[16][CDIM];
  int d = blockIdx.x;
  int lane = threadIdx.x & 63, wv = threadIdx.x >> 6;
  int beg = off[d], deg = off[d + 1] - beg;
  float a0 = 0.f, a1 = 0.f, a2 = 0.f, a3 = 0.f;
  for (int j0 = wv * 64; j0 < deg; j0 += 16 * 64) {
    int myj = j0 + lane;
    int s = (myj < deg) ? adj[beg + myj] : 0;
    int m = min(64, deg - j0);
    int j = 0;
    for (; j + 4 <= m; j += 4) {
      int s0 = __shfl(s, j, 64), s1 = __shfl(s, j + 1, 64);
      int s2 = __shfl(s, j + 2, 64), s3 = __shfl(s, j + 3, 64);
      a0 += x[(size_t)s0 * CDIM + lane];
      a1 += x[(size_t)s1 * CDIM + lane];
      a2 += x[(size_t)s2 * CDIM + lane];
      a3 += x[(size_t)s3 * CDIM + lane];
    }
    for (; j < m; ++j) a0 += x[(size_t)__shfl(s, j, 64) * CDIM + lane];
  }
  red[wv][lane] = (a0 + a1) + (a2 + a3);
  __syncthreads();
  if (wv == 0) {
    float acc = 0.f;
#pragma unroll
    for (int w = 0; w < 16; ++w) acc += red[w][lane];
    out[(size_t)d * CDIM + lane] = (deg > 0) ? acc / (float)deg : 0.f;
  }
}

// ---------------------------------------------------------------------------
// Segmented GEMM: out[m,c] = relu?( sum_seg sum_k A[m,k] * W[c,k] + bias )
// (means already folded into A by the agg kernels)
// ---------------------------------------------------------------------------
struct GemmSeg { const float* A; const float* W; int F; };
struct GemmArgs {
  GemmSeg seg[8];
  const float* bias[4];
  float* out;
  int nseg, nbias, M, relu;
};

__global__ __launch_bounds__(256) void seg_gemm(GemmArgs args) {
  __shared__ __align__(16) float As[64][68];
  __shared__ __align__(16) float Bs[64][68];
  const int tid = threadIdx.x;
  const int tc = tid & 15;
  const int tm = tid >> 4;
  const int m0 = blockIdx.x * 64;
  const int lm = tid >> 4;
  const int lk = (tid & 15) * 4;

  float acc[4][4] = {};

  for (int s = 0; s < args.nseg; ++s) {
    const float* __restrict__ A = args.seg[s].A;
    const float* __restrict__ W = args.seg[s].W;
    const int F = args.seg[s].F;
    for (int k0 = 0; k0 < F; k0 += 64) {
#pragma unroll
      for (int i = 0; i < 4; ++i) {
        int m = i * 16 + lm;
        int gm = m0 + m;
        float4 v = make_float4(0.f, 0.f, 0.f, 0.f);
        if (gm < args.M) v = *(const float4*)(A + (size_t)gm * F + k0 + lk);
        As[lk + 0][m] = v.x; As[lk + 1][m] = v.y;
        As[lk + 2][m] = v.z; As[lk + 3][m] = v.w;
      }
#pragma unroll
      for (int i = 0; i < 4; ++i) {
        int c = i * 16 + lm;
        float4 v = *(const float4*)(W + (size_t)c * F + k0 + lk);
        Bs[lk + 0][c] = v.x; Bs[lk + 1][c] = v.y;
        Bs[lk + 2][c] = v.z; Bs[lk + 3][c] = v.w;
      }
      __syncthreads();
#pragma unroll 8
      for (int k = 0; k < 64; ++k) {
        float4 a = *(const float4*)&As[k][tm * 4];
        float4 w = *(const float4*)&Bs[k][tc * 4];
        acc[0][0] += a.x * w.x; acc[0][1] += a.x * w.y; acc[0][2] += a.x * w.z; acc[0][3] += a.x * w.w;
        acc[1][0] += a.y * w.x; acc[1][1] += a.y * w.y; acc[1][2] += a.y * w.z; acc[1][3] += a.y * w.w;
        acc[2][0] += a.z * w.x; acc[2][1] += a.z * w.y; acc[2][2] += a.z * w.z; acc[2][3] += a.z * w.w;
        acc[3][0] += a.w * w.x; acc[3][1] += a.w * w.y; acc[3][2] += a.w * w.z; acc[3][3] += a.w * w.w;
      }
      __syncthreads();
    }
  }

  float b[4] = {0.f, 0.f, 0.f, 0.f};
  for (int i = 0; i < args.nbias; ++i) {
    const float* bp = args.bias[i];
#pragma unroll
    for (int j = 0; j < 4; ++j) b[j] += bp[tc * 4 + j];
  }
#pragma unroll
  for (int i = 0; i < 4; ++i) {
    int gm = m0 + tm * 4 + i;
    if (gm < args.M) {
      float4 o;
      o.x = acc[i][0] + b[0];
      o.y = acc[i][1] + b[1];
      o.z = acc[i][2] + b[2];
      o.w = acc[i][3] + b[3];
      if (args.relu) {
        o.x = fmaxf(o.x, 0.f); o.y = fmaxf(o.y, 0.f);
        o.z = fmaxf(o.z, 0.f); o.w = fmaxf(o.w, 0.f);
      }
      *(float4*)(args.out + (size_t)gm * CDIM + tc * 4) = o;
    }
  }
}

// ---------------------------------------------------------------------------
// Edge scoring: one wave per edge, wave-reduce dot over 64 channels.
// ---------------------------------------------------------------------------
__global__ __launch_bounds__(256) void score_k(const int* __restrict__ eli, int E,
                                               const float* __restrict__ xu,
                                               const float* __restrict__ xs,
                                               float* __restrict__ out) {
  long long gid = (long long)blockIdx.x * 256 + threadIdx.x;
  int e = (int)(gid >> 6);
  int c = (int)(gid & 63);
  if (e < E) {
    int u = eli[e];
    int sv = eli[E + e];
    float p = xu[(size_t)u * CDIM + c] * xs[(size_t)sv * CDIM + c];
#pragma unroll
    for (int off = 32; off > 0; off >>= 1) p += __shfl_down(p, off, 64);
    if (c == 0) out[e] = p;
  }
}

extern "C" void kernel_launch(void* const* d_in, const int* in_sizes, int n_in,
                              void* d_out, int out_size, void* d_ws, size_t ws_size,
                              hipStream_t stream) {
  const float* reviews  = (const float*)d_in[0];
  const float* overview = (const float*)d_in[1];
  const float* g_emb    = (const float*)d_in[2];
  const float* w_emb    = (const float*)d_in[3];
  const float* t_emb    = (const float*)d_in[4];
  const float* Wu  = (const float*)d_in[5];
  const float* bu  = (const float*)d_in[6];
  const float* Wsp = (const float*)d_in[7];
  const float* bs  = (const float*)d_in[8];
  const float* Wl1 = (const float*)d_in[9];
  const float* bl1 = (const float*)d_in[10];
  const float* Wr1 = (const float*)d_in[11];
  const float* Wl2 = (const float*)d_in[12];
  const float* bl2 = (const float*)d_in[13];
  const float* Wr2 = (const float*)d_in[14];
  const int* e_u2s = (const int*)d_in[15];
  const int* e_g2s = (const int*)d_in[16];
  const int* e_w2s = (const int*)d_in[17];
  const int* e_t2s = (const int*)d_in[18];
  const int* eli   = (const int*)d_in[19];
  const int E_u = in_sizes[15] / 2;
  const int E_g = in_sizes[16] / 2;
  const int E_w = in_sizes[17] / 2;
  const int E_t = in_sizes[18] / 2;
  const int E_l = in_sizes[19] / 2;

  // ---- workspace layout (4B units) ----
  float* ws = (float*)d_ws;
  size_t off = 0;
  auto take = [&](size_t n) { float* p = ws + off; off += n; return p; };
  float* x0u = take((size_t)NU * CDIM);
  float* x0s = take((size_t)NS * CDIM);
  float* x1u = take((size_t)NU * CDIM);
  float* x1s = take((size_t)NS * CDIM);
  float* x1g = take((size_t)NG * CDIM);
  float* x1w = take((size_t)NW * CDIM);
  float* x1t = take((size_t)NT * CDIM);
  // series agg buffers (types 0,2,4,6), contiguous; agg1 aliases aggS0+aggS2
  float* aggS0 = take((size_t)NS * CDIM);
  float* aggS2 = take((size_t)NS * CDIM);
  float* aggS4 = take((size_t)NS * CDIM);
  float* aggS6 = take((size_t)NS * CDIM);
  float* agg1  = aggS0;  // [NU*CDIM] alias over aggS0+aggS2 (lifetimes disjoint)
  float* agg3  = take((size_t)NG * CDIM);
  float* agg5  = take((size_t)NW * CDIM);
  float* agg7  = take((size_t)NT * CDIM);
  int* adj0 = (int*)take(E_u);
  int* adj1 = (int*)take(E_u);
  int* adj2 = (int*)take(E_g);
  int* adj3 = (int*)take(E_g);
  int* adj4 = (int*)take(E_w);
  int* adj5 = (int*)take(E_w);
  int* adj6 = (int*)take(E_t);
  int* adj7 = (int*)take(E_t);
  int* off0 = (int*)take(NS + 1);
  int* off1 = (int*)take(NU + 1);
  int* off2 = (int*)take(NS + 1);
  int* off3 = (int*)take(NG + 1);
  int* off4 = (int*)take(NS + 1);
  int* off5 = (int*)take(NW + 1);
  int* off6 = (int*)take(NS + 1);
  int* off7 = (int*)take(NT + 1);
  int* partial = (int*)take((size_t)HG * TOTB);
  int* cntall  = (int*)take(TOTB);
  // x2 aliases x0 (dead after layer-1 reads complete)
  float* x2u = x0u;
  float* x2s = x0s;

  // ---- CSR args (all 8 edge types, unified bin space) ----
  CsrArgs ca{};
  const int* srcs[8] = {e_u2s,       e_u2s + E_u, e_g2s,       e_g2s + E_g,
                        e_w2s,       e_w2s + E_w, e_t2s,       e_t2s + E_t};
  const int* dsts[8] = {e_u2s + E_u, e_u2s,       e_g2s + E_g, e_g2s,
                        e_w2s + E_w, e_w2s,       e_t2s + E_t, e_t2s};
  int Es[8]  = {E_u, E_u, E_g, E_g, E_w, E_w, E_t, E_t};
  int nbs[8] = {NS, NU, NS, NG, NS, NW, NS, NT};
  int* offs[8] = {off0, off1, off2, off3, off4, off5, off6, off7};
  int* adjs[8] = {adj0, adj1, adj2, adj3, adj4, adj5, adj6, adj7};
  int base = 0;
  for (int i = 0; i < 8; ++i) {
    ca.src[i] = srcs[i]; ca.dst[i] = dsts[i];
    ca.E[i] = Es[i]; ca.nb[i] = nbs[i]; ca.base[i] = base; base += nbs[i];
    ca.off[i] = offs[i]; ca.adj[i] = adjs[i];
  }
  ca.partial = partial; ca.cnt = cntall;

  // ---- CSR build (4 dispatches, zero global atomics) ----
  hist_all<<<8 * HG, 256, 0, stream>>>(ca);
  scan_blocks_all<<<(TOTB + 255) / 256, 256, 0, stream>>>(partial, cntall);
  scan_off_all<<<8, 1024, 0, stream>>>(ca);
  fill_all<<<8 * HG, 256, 0, stream>>>(ca);

  // ---- projections ----
  {
    GemmArgs a{};
    a.seg[0] = {reviews, Wu, FDIM}; a.nseg = 1;
    a.bias[0] = bu; a.nbias = 1;
    a.out = x0u; a.M = NU; a.relu = 0;
    seg_gemm<<<(NU + 63) / 64, 256, 0, stream>>>(a);
  }
  {
    GemmArgs a{};
    a.seg[0] = {overview, Wsp, FDIM}; a.nseg = 1;
    a.bias[0] = bs; a.nbias = 1;
    a.out = x0s; a.M = NS; a.relu = 0;
    seg_gemm<<<(NS + 63) / 64, 256, 0, stream>>>(a);
  }

  // ---- layer 1: series-dst aggregations (types 0,2,4,6) + series GEMM ----
  {
    Agg4Args a{};
    a.adj[0] = adj0; a.off[0] = off0; a.x[0] = x0u;   a.out[0] = aggS0;
    a.adj[1] = adj2; a.off[1] = off2; a.x[1] = g_emb; a.out[1] = aggS2;
    a.adj[2] = adj4; a.off[2] = off4; a.x[2] = w_emb; a.out[2] = aggS4;
    a.adj[3] = adj6; a.off[3] = off6; a.x[3] = t_emb; a.out[3] = aggS6;
    dim3 grid((NS * 64 + 255) / 256, 4);
    agg_series4_k<<<grid, 256, 0, stream>>>(a);
  }
  {
    GemmArgs a{};
    a.seg[0] = {aggS0, Wl1 + 0 * 4096, 64};
    a.seg[1] = {aggS2, Wl1 + 2 * 4096, 64};
    a.seg[2] = {aggS4, Wl1 + 4 * 4096, 64};
    a.seg[3] = {aggS6, Wl1 + 6 * 4096, 64};
    a.seg[4] = {x0s, Wr1 + 0 * 4096, 64};
    a.seg[5] = {x0s, Wr1 + 2 * 4096, 64};
    a.seg[6] = {x0s, Wr1 + 4 * 4096, 64};
    a.seg[7] = {x0s, Wr1 + 6 * 4096, 64};
    a.nseg = 8;
    a.bias[0] = bl1 + 0 * 64; a.bias[1] = bl1 + 2 * 64;
    a.bias[2] = bl1 + 4 * 64; a.bias[3] = bl1 + 6 * 64; a.nbias = 4;
    a.out = x1s; a.M = NS; a.relu = 1;
    seg_gemm<<<(NS + 63) / 64, 256, 0, stream>>>(a);
  }
  // users (agg1 aliases aggS0/aggS2 — safe now, series GEMM already consumed)
  agg_gather_k<<<(NU * 64 + 255) / 256, 256, 0, stream>>>(adj1, off1, x0s, agg1, NU);
  {
    GemmArgs a{};
    a.seg[0] = {agg1, Wl1 + 1 * 4096, 64};
    a.seg[1] = {x0u, Wr1 + 1 * 4096, 64};
    a.nseg = 2;
    a.bias[0] = bl1 + 1 * 64; a.nbias = 1;
    a.out = x1u; a.M = NU; a.relu = 1;
    seg_gemm<<<(NU + 63) / 64, 256, 0, stream>>>(a);
  }
  // genres / writer / type
  agg_dense_k<<<NG, 1024, 0, stream>>>(adj3, off3, x0s, agg3, NG);
  {
    GemmArgs a{};
    a.seg[0] = {agg3, Wl1 + 3 * 4096, 64};
    a.seg[1] = {g_emb, Wr1 + 3 * 4096, 64};
    a.nseg = 2;
    a.bias[0] = bl1 + 3 * 64; a.nbias = 1;
    a.out = x1g; a.M = NG; a.relu = 1;
    seg_gemm<<<(NG + 63) / 64, 256, 0, stream>>>(a);
  }
  agg_gather_k<<<(NW * 64 + 255) / 256, 256, 0, stream>>>(adj5, off5, x0s, agg5, NW);
  {
    GemmArgs a{};
    a.seg[0] = {agg5, Wl1 + 5 * 4096, 64};
    a.seg[1] = {w_emb, Wr1 + 5 * 4096, 64};
    a.nseg = 2;
    a.bias[0] = bl1 + 5 * 64; a.nbias = 1;
    a.out = x1w; a.M = NW; a.relu = 1;
    seg_gemm<<<(NW + 63) / 64, 256, 0, stream>>>(a);
  }
  agg_dense_k<<<NT, 1024, 0, stream>>>(adj7, off7, x0s, agg7, NT);
  {
    GemmArgs a{};
    a.seg[0] = {agg7, Wl1 + 7 * 4096, 64};
    a.seg[1] = {t_emb, Wr1 + 7 * 4096, 64};
    a.nseg = 2;
    a.bias[0] = bl1 + 7 * 64; a.nbias = 1;
    a.out = x1t; a.M = NT; a.relu = 1;
    seg_gemm<<<(NT + 63) / 64, 256, 0, stream>>>(a);
  }

  // ---- layer 2: series aggs + GEMM, then users ----
  {
    Agg4Args a{};
    a.adj[0] = adj0; a.off[0] = off0; a.x[0] = x1u; a.out[0] = aggS0;
    a.adj[1] = adj2; a.off[1] = off2; a.x[1] = x1g; a.out[1] = aggS2;
    a.adj[2] = adj4; a.off[2] = off4; a.x[2] = x1w; a.out[2] = aggS4;
    a.adj[3] = adj6; a.off[3] = off6; a.x[3] = x1t; a.out[3] = aggS6;
    dim3 grid((NS * 64 + 255) / 256, 4);
    agg_series4_k<<<grid, 256, 0, stream>>>(a);
  }
  {
    GemmArgs a{};
    a.seg[0] = {aggS0, Wl2 + 0 * 4096, 64};
    a.seg[1] = {aggS2, Wl2 + 2 * 4096, 64};
    a.seg[2] = {aggS4, Wl2 + 4 * 4096, 64};
    a.seg[3] = {aggS6, Wl2 + 6 * 4096, 64};
    a.seg[4] = {x1s, Wr2 + 0 * 4096, 64};
    a.seg[5] = {x1s, Wr2 + 2 * 4096, 64};
    a.seg[6] = {x1s, Wr2 + 4 * 4096, 64};
    a.seg[7] = {x1s, Wr2 + 6 * 4096, 64};
    a.nseg = 8;
    a.bias[0] = bl2 + 0 * 64; a.bias[1] = bl2 + 2 * 64;
    a.bias[2] = bl2 + 4 * 64; a.bias[3] = bl2 + 6 * 64; a.nbias = 4;
    a.out = x2s; a.M = NS; a.relu = 0;
    seg_gemm<<<(NS + 63) / 64, 256, 0, stream>>>(a);
  }
  agg_gather_k<<<(NU * 64 + 255) / 256, 256, 0, stream>>>(adj1, off1, x1s, agg1, NU);
  {
    GemmArgs a{};
    a.seg[0] = {agg1, Wl2 + 1 * 4096, 64};
    a.seg[1] = {x1u, Wr2 + 1 * 4096, 64};
    a.nseg = 2;
    a.bias[0] = bl2 + 1 * 64; a.nbias = 1;
    a.out = x2u; a.M = NU; a.relu = 0;
    seg_gemm<<<(NU + 63) / 64, 256, 0, stream>>>(a);
  }

  // ---- scoring ----
  score_k<<<((long long)E_l * 64 + 255) / 256, 256, 0, stream>>>(
      eli, E_l, x2u, x2s, (float*)d_out);
}